// Round 1
// baseline (259.734 us; speedup 1.0000x reference)
//
#include <hip/hip_runtime.h>

typedef short short8 __attribute__((ext_vector_type(8)));
typedef float f32x4 __attribute__((ext_vector_type(4)));

#define AS1 __attribute__((address_space(1)))
#define AS3 __attribute__((address_space(3)))

__device__ __forceinline__ void gload16(const void* g, void* l) {
    __builtin_amdgcn_global_load_lds((const AS1 unsigned int*)g, (AS3 unsigned int*)l, 16, 0, 0);
}

__device__ __forceinline__ unsigned short f2bf(float f) {
    union { float f; unsigned u; } c; c.f = f;
    unsigned r = (c.u + 0x7FFFu + ((c.u >> 16) & 1u)) >> 16;
    return (unsigned short)r;
}

__device__ __forceinline__ void mfma16(f32x4& d, short8 a, short8 b) {
    asm("v_mfma_f32_16x16x32_bf16 %0, %1, %2, %0" : "+v"(d) : "v"(a), "v"(b));
}

// ---------------- fp32 -> bf16 convert ----------------
__global__ __launch_bounds__(256) void cvt_f32_bf16(const float* __restrict__ in,
                                                    unsigned short* __restrict__ out, int n4) {
    int idx = blockIdx.x * 256 + threadIdx.x;
    int stride = gridDim.x * 256;
    for (int i = idx; i < n4; i += stride) {
        float4 v = ((const float4*)in)[i];
        ushort4 o;
        o.x = f2bf(v.x); o.y = f2bf(v.y); o.z = f2bf(v.z); o.w = f2bf(v.w);
        ((ushort4*)out)[i] = o;
    }
}

// ---------------- NT GEMM: C[M,N] = A[M,K] * B[N,K]^T (+bias) ----------------
// EPI=0: QKV epilogue -> split q(scaled)/k into [BH,S,64], v transposed into [BH,64,S], all bf16
// EPI=1: fp32 out + bias
template <int EPI>
__global__ __launch_bounds__(256) void gemm_nt(
    const unsigned short* __restrict__ A, const unsigned short* __restrict__ B,
    const float* __restrict__ bias, int M, int N, int K,
    float* __restrict__ Cf, unsigned short* __restrict__ qb,
    unsigned short* __restrict__ kb, unsigned short* __restrict__ vtb) {
    __shared__ unsigned short As[128 * 64];
    __shared__ unsigned short Bs[128 * 64];
    const int tid = threadIdx.x;
    const int lane = tid & 63;
    const int wv = tid >> 6;
    const int wm = (wv >> 1) * 64, wn = (wv & 1) * 64;
    const int lr = lane & 15, lg = lane >> 4;
    const int m0 = blockIdx.x * 128, n0 = blockIdx.y * 128;

    f32x4 acc[4][4];
#pragma unroll
    for (int i = 0; i < 4; i++)
#pragma unroll
        for (int j = 0; j < 4; j++) acc[i][j] = (f32x4){0.f, 0.f, 0.f, 0.f};

    const int sr = tid >> 3;         // staging row 0..31 (per 32-row chunk)
    const int sc = (tid & 7) * 8;    // staging col (elements)
    const unsigned short* Ag = A + (size_t)(m0 + sr) * K + sc;
    const unsigned short* Bg = B + (size_t)(n0 + sr) * K + sc;
    unsigned short* Asl = As + tid * 8;
    unsigned short* Bsl = Bs + tid * 8;

    for (int kt = 0; kt < K; kt += 64) {
        __syncthreads();
#pragma unroll
        for (int i = 0; i < 4; i++) {
            gload16(Ag + (size_t)(i * 32) * K + kt, Asl + i * 2048);
            gload16(Bg + (size_t)(i * 32) * K + kt, Bsl + i * 2048);
        }
        __syncthreads();
#pragma unroll
        for (int ks = 0; ks < 2; ks++) {
            short8 af[4], bf[4];
#pragma unroll
            for (int mi = 0; mi < 4; mi++)
                af[mi] = *(const short8*)(As + (wm + mi * 16 + lr) * 64 + ks * 32 + lg * 8);
#pragma unroll
            for (int ni = 0; ni < 4; ni++)
                bf[ni] = *(const short8*)(Bs + (wn + ni * 16 + lr) * 64 + ks * 32 + lg * 8);
#pragma unroll
            for (int mi = 0; mi < 4; mi++)
#pragma unroll
                for (int ni = 0; ni < 4; ni++) mfma16(acc[mi][ni], af[mi], bf[ni]);
        }
    }

#pragma unroll
    for (int mi = 0; mi < 4; mi++) {
#pragma unroll
        for (int ni = 0; ni < 4; ni++) {
            const int col = n0 + wn + ni * 16 + lr;
            const float bia = bias[col];
#pragma unroll
            for (int r = 0; r < 4; r++) {
                const int row = m0 + wm + mi * 16 + lg * 4 + r;
                float v = acc[mi][ni][r] + bia;
                if (EPI == 0) {
                    const int b = row >> 10, s = row & 1023;
                    const unsigned h = (unsigned)col / 192u;
                    const int rem = col - (int)h * 192;
                    const int t = rem >> 6, d = rem & 63;
                    const int bh = b * 16 + (int)h;
                    if (t == 0) {
                        qb[((size_t)bh * 1024 + s) * 64 + d] = f2bf(v * 0.125f);
                    } else if (t == 1) {
                        kb[((size_t)bh * 1024 + s) * 64 + d] = f2bf(v);
                    } else {
                        vtb[((size_t)bh * 64 + d) * 1024 + s] = f2bf(v);
                    }
                } else {
                    Cf[(size_t)row * N + col] = v;
                }
            }
        }
    }
}

// ---------------- flash attention ----------------
// q [BH,S,64] bf16 (pre-scaled by 1/8), k [BH,S,64] bf16, vt [BH,64,S] bf16
// out: vals [B*S, E] bf16 with column h*64+d
__global__ __launch_bounds__(256) void attn_fwd(
    const unsigned short* __restrict__ qg, const unsigned short* __restrict__ kg,
    const unsigned short* __restrict__ vtg, unsigned short* __restrict__ vals) {
    __shared__ unsigned short Ks[64 * 64];
    __shared__ unsigned short Vts[64 * 64];
    __shared__ unsigned short Ps[4 * 16 * 64];
    const int tid = threadIdx.x, lane = tid & 63, w = tid >> 6;
    const int lr = lane & 15, lg = lane >> 4;
    const int bh = blockIdx.y;
    const int qb0 = blockIdx.x * 64;

    const size_t qoff = ((size_t)bh * 1024 + qb0 + w * 16 + lr) * 64 + lg * 8;
    const short8 aq0 = *(const short8*)(qg + qoff);
    const short8 aq1 = *(const short8*)(qg + qoff + 32);

    f32x4 o[4];
    float m_r[4], l_r[4];
#pragma unroll
    for (int i = 0; i < 4; i++) {
        o[i] = (f32x4){0.f, 0.f, 0.f, 0.f};
        m_r[i] = -1e30f;
        l_r[i] = 0.f;
    }

    const unsigned short* kbase0 = kg + (size_t)bh * 1024 * 64;
    const unsigned short* vbase0 = vtg + (size_t)bh * 64 * 1024;
    unsigned short* pw = Ps + w * 1024;

    for (int kv0 = 0; kv0 < 1024; kv0 += 64) {
        __syncthreads();
#pragma unroll
        for (int i = 0; i < 2; i++) {
            gload16(kbase0 + (size_t)kv0 * 64 + i * 2048 + tid * 8, Ks + i * 2048 + tid * 8);
            gload16(vbase0 + (size_t)(i * 32 + (tid >> 3)) * 1024 + kv0 + (tid & 7) * 8,
                    Vts + i * 2048 + tid * 8);
        }
        __syncthreads();

        f32x4 s[4];
#pragma unroll
        for (int i = 0; i < 4; i++) s[i] = (f32x4){0.f, 0.f, 0.f, 0.f};
#pragma unroll
        for (int ks = 0; ks < 2; ks++) {
            const short8 aq = ks ? aq1 : aq0;
#pragma unroll
            for (int ni = 0; ni < 4; ni++) {
                short8 bk = *(const short8*)(Ks + (ni * 16 + lr) * 64 + ks * 32 + lg * 8);
                mfma16(s[ni], aq, bk);
            }
        }

        float mx[4], alpha[4], rs[4], p[4][4];
#pragma unroll
        for (int r = 0; r < 4; r++)
            mx[r] = fmaxf(fmaxf(s[0][r], s[1][r]), fmaxf(s[2][r], s[3][r]));
#pragma unroll
        for (int off = 1; off < 16; off <<= 1)
#pragma unroll
            for (int r = 0; r < 4; r++) mx[r] = fmaxf(mx[r], __shfl_xor(mx[r], off));
#pragma unroll
        for (int r = 0; r < 4; r++) {
            const float mn = fmaxf(m_r[r], mx[r]);
            alpha[r] = __expf(m_r[r] - mn);
            m_r[r] = mn;
        }
#pragma unroll
        for (int ni = 0; ni < 4; ni++)
#pragma unroll
            for (int r = 0; r < 4; r++) p[ni][r] = __expf(s[ni][r] - m_r[r]);
#pragma unroll
        for (int r = 0; r < 4; r++) rs[r] = (p[0][r] + p[1][r]) + (p[2][r] + p[3][r]);
#pragma unroll
        for (int off = 1; off < 16; off <<= 1)
#pragma unroll
            for (int r = 0; r < 4; r++) rs[r] += __shfl_xor(rs[r], off);
#pragma unroll
        for (int r = 0; r < 4; r++) l_r[r] = l_r[r] * alpha[r] + rs[r];
#pragma unroll
        for (int ni = 0; ni < 4; ni++)
#pragma unroll
            for (int r = 0; r < 4; r++) o[ni][r] *= alpha[r];

#pragma unroll
        for (int ni = 0; ni < 4; ni++)
#pragma unroll
            for (int r = 0; r < 4; r++)
                pw[(lg * 4 + r) * 64 + ni * 16 + lr] = f2bf(p[ni][r]);

#pragma unroll
        for (int ks2 = 0; ks2 < 2; ks2++) {
            const short8 pa = *(const short8*)(pw + lr * 64 + ks2 * 32 + lg * 8);
#pragma unroll
            for (int ni = 0; ni < 4; ni++) {
                short8 bv = *(const short8*)(Vts + (ni * 16 + lr) * 64 + ks2 * 32 + lg * 8);
                mfma16(o[ni], pa, bv);
            }
        }
    }

    const int b = bh >> 4, h = bh & 15;
#pragma unroll
    for (int r = 0; r < 4; r++) {
        const float inv = 1.f / l_r[r];
        const size_t row = (size_t)b * 1024 + qb0 + w * 16 + lg * 4 + r;
#pragma unroll
        for (int ni = 0; ni < 4; ni++)
            vals[row * 1024 + h * 64 + ni * 16 + lr] = f2bf(o[ni][r] * inv);
    }
}

extern "C" void kernel_launch(void* const* d_in, const int* in_sizes, int n_in,
                              void* d_out, int out_size, void* d_ws, size_t ws_size,
                              hipStream_t stream) {
    const float* x = (const float*)d_in[0];
    const float* w_in = (const float*)d_in[1];
    const float* b_in = (const float*)d_in[2];
    const float* w_out = (const float*)d_in[3];
    const float* b_out = (const float*)d_in[4];
    float* out = (float*)d_out;

    // workspace layout (ushort elements). vals aliases xb (xb dead after QKV GEMM).
    unsigned short* ws = (unsigned short*)d_ws;
    unsigned short* xb = ws;                   // 8388608  (also reused as vals)
    unsigned short* winb = xb + 8388608;       // 3145728
    unsigned short* woutb = winb + 3145728;    // 1048576
    unsigned short* qb = woutb + 1048576;      // 8388608
    unsigned short* kb = qb + 8388608;         // 8388608
    unsigned short* vtb = kb + 8388608;        // 8388608
    unsigned short* vals = xb;                 // alias

    cvt_f32_bf16<<<2048, 256, 0, stream>>>(x, xb, 8388608 / 4);
    cvt_f32_bf16<<<1024, 256, 0, stream>>>(w_in, winb, 3145728 / 4);
    cvt_f32_bf16<<<512, 256, 0, stream>>>(w_out, woutb, 1048576 / 4);

    gemm_nt<0><<<dim3(64, 24), 256, 0, stream>>>(xb, winb, b_in, 8192, 3072, 1024,
                                                 nullptr, qb, kb, vtb);
    attn_fwd<<<dim3(16, 128), 256, 0, stream>>>(qb, kb, vtb, vals);
    gemm_nt<1><<<dim3(64, 8), 256, 0, stream>>>(vals, woutb, b_out, 8192, 1024, 1024,
                                                out, nullptr, nullptr, nullptr);
}

// Round 2
// 190.475 us; speedup vs baseline: 1.3636x; 1.3636x over previous
//
#include <hip/hip_runtime.h>

typedef short short8 __attribute__((ext_vector_type(8)));
typedef float f32x4 __attribute__((ext_vector_type(4)));

#define AS1 __attribute__((address_space(1)))
#define AS3 __attribute__((address_space(3)))

__device__ __forceinline__ void gload16(const void* g, void* l) {
    __builtin_amdgcn_global_load_lds((const AS1 unsigned int*)g, (AS3 unsigned int*)l, 16, 0, 0);
}

__device__ __forceinline__ unsigned short f2bf(float f) {
    union { float f; unsigned u; } c; c.f = f;
    unsigned r = (c.u + 0x7FFFu + ((c.u >> 16) & 1u)) >> 16;
    return (unsigned short)r;
}

__device__ __forceinline__ unsigned cvtpk(float a, float b) {
    unsigned r;
    asm("v_cvt_pk_bf16_f32 %0, %1, %2" : "=v"(r) : "v"(a), "v"(b));
    return r;
}

__device__ __forceinline__ void mfma16(f32x4& d, short8 a, short8 b) {
    asm("v_mfma_f32_16x16x32_bf16 %0, %1, %2, %0" : "+v"(d) : "v"(a), "v"(b));
}

// q pre-scale: 1/sqrt(64) * log2(e)  -> softmax via exp2
#define QSCALE 0.18033688011112042f

// ---------------- fp32 -> bf16 convert ----------------
__global__ __launch_bounds__(256) void cvt_f32_bf16(const float* __restrict__ in,
                                                    unsigned short* __restrict__ out, int n4) {
    int idx = blockIdx.x * 256 + threadIdx.x;
    int stride = gridDim.x * 256;
    for (int i = idx; i < n4; i += stride) {
        float4 v = ((const float4*)in)[i];
        ushort4 o;
        o.x = f2bf(v.x); o.y = f2bf(v.y); o.z = f2bf(v.z); o.w = f2bf(v.w);
        ((ushort4*)out)[i] = o;
    }
}

// ---------------- NT GEMM: C[M,N] = A[M,K] * B[N,K]^T (+bias) ----------------
template <int EPI>
__global__ __launch_bounds__(256) void gemm_nt(
    const unsigned short* __restrict__ A, const unsigned short* __restrict__ B,
    const float* __restrict__ bias, int M, int N, int K,
    float* __restrict__ Cf, unsigned short* __restrict__ qb,
    unsigned short* __restrict__ kb, unsigned short* __restrict__ vtb) {
    __shared__ unsigned short As[128 * 64];
    __shared__ unsigned short Bs[128 * 64];
    const int tid = threadIdx.x;
    const int lane = tid & 63;
    const int wv = tid >> 6;
    const int wm = (wv >> 1) * 64, wn = (wv & 1) * 64;
    const int lr = lane & 15, lg = lane >> 4;
    const int m0 = blockIdx.x * 128, n0 = blockIdx.y * 128;

    f32x4 acc[4][4];
#pragma unroll
    for (int i = 0; i < 4; i++)
#pragma unroll
        for (int j = 0; j < 4; j++) acc[i][j] = (f32x4){0.f, 0.f, 0.f, 0.f};

    const int sr = tid >> 3;
    const int sc = (tid & 7) * 8;
    const unsigned short* Ag = A + (size_t)(m0 + sr) * K + sc;
    const unsigned short* Bg = B + (size_t)(n0 + sr) * K + sc;
    unsigned short* Asl = As + tid * 8;
    unsigned short* Bsl = Bs + tid * 8;

    for (int kt = 0; kt < K; kt += 64) {
        __syncthreads();
#pragma unroll
        for (int i = 0; i < 4; i++) {
            gload16(Ag + (size_t)(i * 32) * K + kt, Asl + i * 2048);
            gload16(Bg + (size_t)(i * 32) * K + kt, Bsl + i * 2048);
        }
        __syncthreads();
#pragma unroll
        for (int ks = 0; ks < 2; ks++) {
            short8 af[4], bf[4];
#pragma unroll
            for (int mi = 0; mi < 4; mi++)
                af[mi] = *(const short8*)(As + (wm + mi * 16 + lr) * 64 + ks * 32 + lg * 8);
#pragma unroll
            for (int ni = 0; ni < 4; ni++)
                bf[ni] = *(const short8*)(Bs + (wn + ni * 16 + lr) * 64 + ks * 32 + lg * 8);
#pragma unroll
            for (int mi = 0; mi < 4; mi++)
#pragma unroll
                for (int ni = 0; ni < 4; ni++) mfma16(acc[mi][ni], af[mi], bf[ni]);
        }
    }

#pragma unroll
    for (int mi = 0; mi < 4; mi++) {
#pragma unroll
        for (int ni = 0; ni < 4; ni++) {
            const int col = n0 + wn + ni * 16 + lr;
            const float bia = bias[col];
#pragma unroll
            for (int r = 0; r < 4; r++) {
                const int row = m0 + wm + mi * 16 + lg * 4 + r;
                float v = acc[mi][ni][r] + bia;
                if (EPI == 0) {
                    const int b = row >> 10, s = row & 1023;
                    const unsigned h = (unsigned)col / 192u;
                    const int rem = col - (int)h * 192;
                    const int t = rem >> 6, d = rem & 63;
                    const int bh = b * 16 + (int)h;
                    if (t == 0) {
                        qb[((size_t)bh * 1024 + s) * 64 + d] = f2bf(v * QSCALE);
                    } else if (t == 1) {
                        kb[((size_t)bh * 1024 + s) * 64 + d] = f2bf(v);
                    } else {
                        vtb[((size_t)bh * 64 + d) * 1024 + s] = f2bf(v);
                    }
                } else {
                    Cf[(size_t)row * N + col] = v;
                }
            }
        }
    }
}

// ---------------- flash attention (swapped QK^T / swapped PV, swizzled LDS) ----------------
// S^T = mfma(K, Q): lane holds S[k = kt*16+lg*4+r][q = lr] -> softmax stats lane-local in q
// O^T = mfma(Vt, P): o[mi][r] = O[q=lr][d = mi*16+lg*4+r]
__device__ __forceinline__ void softmax_half(f32x4 (&s)[4], float& m, float& l,
                                             f32x4 (&o)[4], unsigned short* pbuf,
                                             int lr, int lg, int x7) {
    float mx = s[0][0];
#pragma unroll
    for (int kt = 0; kt < 4; kt++)
#pragma unroll
        for (int r = 0; r < 4; r++) mx = fmaxf(mx, s[kt][r]);
    mx = fmaxf(mx, __shfl_xor(mx, 16));
    mx = fmaxf(mx, __shfl_xor(mx, 32));
    const float mn = fmaxf(m, mx);
    const float alpha = __builtin_amdgcn_exp2f(m - mn);
    m = mn;
    float p[4][4];
    float rs = 0.f;
#pragma unroll
    for (int kt = 0; kt < 4; kt++)
#pragma unroll
        for (int r = 0; r < 4; r++) {
            p[kt][r] = __builtin_amdgcn_exp2f(s[kt][r] - mn);
            rs += p[kt][r];
        }
    rs += __shfl_xor(rs, 16);
    rs += __shfl_xor(rs, 32);
    l = l * alpha + rs;
#pragma unroll
    for (int mi = 0; mi < 4; mi++)
#pragma unroll
        for (int r = 0; r < 4; r++) o[mi][r] *= alpha;
    // packed swizzled P write: P[q=lr][k = kt*16+lg*4+2w] as b32 pairs
#pragma unroll
    for (int kt = 0; kt < 4; kt++)
#pragma unroll
        for (int w2 = 0; w2 < 2; w2++) {
            const unsigned pk = cvtpk(p[kt][2 * w2], p[kt][2 * w2 + 1]);
            const int col = (kt * 16 + lg * 4 + 2 * w2) ^ (x7 << 3);
            *(unsigned*)(pbuf + lr * 64 + col) = pk;
        }
}

__global__ __launch_bounds__(256) void attn_fwd(
    const unsigned short* __restrict__ qg, const unsigned short* __restrict__ kg,
    const unsigned short* __restrict__ vtg, unsigned short* __restrict__ vals) {
    __shared__ unsigned short Ks[64 * 64];
    __shared__ unsigned short Vts[64 * 64];
    __shared__ unsigned short Ps[4 * 2048];  // per wave: [2 halves][16 q][64 k]
    const int tid = threadIdx.x, lane = tid & 63, w = tid >> 6;
    const int lr = lane & 15, lg = lane >> 4;
    const int x7 = lr & 7;
    const int bh = blockIdx.y;
    const int q0 = blockIdx.x * 128 + w * 32;

    // Q fragments (B-operand layout: n=lr is the q row, k-slice lg*8)
    const unsigned short* qrowA = qg + ((size_t)bh * 1024 + q0 + lr) * 64;
    const unsigned short* qrowB = qrowA + 16 * 64;
    short8 qA[2], qB[2];
    qA[0] = *(const short8*)(qrowA + lg * 8);
    qA[1] = *(const short8*)(qrowA + 32 + lg * 8);
    qB[0] = *(const short8*)(qrowB + lg * 8);
    qB[1] = *(const short8*)(qrowB + 32 + lg * 8);

    f32x4 oA[4], oB[4];
    float mA = -1e30f, mB = -1e30f, lA = 0.f, lB = 0.f;
#pragma unroll
    for (int i = 0; i < 4; i++) {
        oA[i] = (f32x4){0.f, 0.f, 0.f, 0.f};
        oB[i] = (f32x4){0.f, 0.f, 0.f, 0.f};
    }

    const unsigned short* kb = kg + (size_t)bh * 65536;
    const unsigned short* vb = vtg + (size_t)bh * 65536;
    unsigned short* pwl = Ps + w * 2048;

    const int srow = tid >> 3;                       // 0..31
    const int scol = ((tid & 7) ^ (srow & 7)) * 8;   // pre-swizzled global source col

    for (int kv0 = 0; kv0 < 1024; kv0 += 64) {
        __syncthreads();
#pragma unroll
        for (int i = 0; i < 2; i++) {
            gload16(kb + (size_t)(kv0 + i * 32 + srow) * 64 + scol, Ks + i * 2048 + tid * 8);
            gload16(vb + (size_t)(i * 32 + srow) * 1024 + kv0 + scol, Vts + i * 2048 + tid * 8);
        }
        __syncthreads();

        // QK^T (swapped): s[kt] accumulates S^T[16 k rows][16 q]
        f32x4 sA[4], sB[4];
#pragma unroll
        for (int i = 0; i < 4; i++) {
            sA[i] = (f32x4){0.f, 0.f, 0.f, 0.f};
            sB[i] = (f32x4){0.f, 0.f, 0.f, 0.f};
        }
#pragma unroll
        for (int kt = 0; kt < 4; kt++) {
            const short8 k0 = *(const short8*)(Ks + (kt * 16 + lr) * 64 + ((0 + lg) ^ x7) * 8);
            const short8 k1 = *(const short8*)(Ks + (kt * 16 + lr) * 64 + ((4 + lg) ^ x7) * 8);
            mfma16(sA[kt], k0, qA[0]);
            mfma16(sB[kt], k0, qB[0]);
            mfma16(sA[kt], k1, qA[1]);
            mfma16(sB[kt], k1, qB[1]);
        }

        softmax_half(sA, mA, lA, oA, pwl, lr, lg, x7);
        softmax_half(sB, mB, lB, oB, pwl + 1024, lr, lg, x7);

        // P fragments (B-operand): P[q=lr][ks2*32+lg*8 ..]
        short8 pA[2], pB[2];
#pragma unroll
        for (int ks2 = 0; ks2 < 2; ks2++) {
            pA[ks2] = *(const short8*)(pwl + lr * 64 + (((ks2 * 4 + lg) ^ x7) * 8));
            pB[ks2] = *(const short8*)(pwl + 1024 + lr * 64 + (((ks2 * 4 + lg) ^ x7) * 8));
        }
        // PV (swapped): o^T += Vt · P^T
#pragma unroll
        for (int mi = 0; mi < 4; mi++) {
            const short8 v0 = *(const short8*)(Vts + (mi * 16 + lr) * 64 + ((0 + lg) ^ x7) * 8);
            const short8 v1 = *(const short8*)(Vts + (mi * 16 + lr) * 64 + ((4 + lg) ^ x7) * 8);
            mfma16(oA[mi], v0, pA[0]);
            mfma16(oB[mi], v0, pB[0]);
            mfma16(oA[mi], v1, pA[1]);
            mfma16(oB[mi], v1, pB[1]);
        }
    }

    const int bb = bh >> 4, hh = bh & 15;
    {
        const float inv = 1.f / lA;
        unsigned short* vp = vals + (size_t)(bb * 1024 + q0 + lr) * 1024 + hh * 64 + lg * 4;
#pragma unroll
        for (int mi = 0; mi < 4; mi++) {
            uint2 st;
            st.x = cvtpk(oA[mi][0] * inv, oA[mi][1] * inv);
            st.y = cvtpk(oA[mi][2] * inv, oA[mi][3] * inv);
            *(uint2*)(vp + mi * 16) = st;
        }
    }
    {
        const float inv = 1.f / lB;
        unsigned short* vp = vals + (size_t)(bb * 1024 + q0 + 16 + lr) * 1024 + hh * 64 + lg * 4;
#pragma unroll
        for (int mi = 0; mi < 4; mi++) {
            uint2 st;
            st.x = cvtpk(oB[mi][0] * inv, oB[mi][1] * inv);
            st.y = cvtpk(oB[mi][2] * inv, oB[mi][3] * inv);
            *(uint2*)(vp + mi * 16) = st;
        }
    }
}

extern "C" void kernel_launch(void* const* d_in, const int* in_sizes, int n_in,
                              void* d_out, int out_size, void* d_ws, size_t ws_size,
                              hipStream_t stream) {
    const float* x = (const float*)d_in[0];
    const float* w_in = (const float*)d_in[1];
    const float* b_in = (const float*)d_in[2];
    const float* w_out = (const float*)d_in[3];
    const float* b_out = (const float*)d_in[4];
    float* out = (float*)d_out;

    unsigned short* ws = (unsigned short*)d_ws;
    unsigned short* xb = ws;                   // 8388608  (reused as vals)
    unsigned short* winb = xb + 8388608;       // 3145728
    unsigned short* woutb = winb + 3145728;    // 1048576
    unsigned short* qb = woutb + 1048576;      // 8388608
    unsigned short* kb = qb + 8388608;         // 8388608
    unsigned short* vtb = kb + 8388608;        // 8388608
    unsigned short* vals = xb;                 // alias

    cvt_f32_bf16<<<2048, 256, 0, stream>>>(x, xb, 8388608 / 4);
    cvt_f32_bf16<<<1024, 256, 0, stream>>>(w_in, winb, 3145728 / 4);
    cvt_f32_bf16<<<512, 256, 0, stream>>>(w_out, woutb, 1048576 / 4);

    gemm_nt<0><<<dim3(64, 24), 256, 0, stream>>>(xb, winb, b_in, 8192, 3072, 1024,
                                                 nullptr, qb, kb, vtb);
    attn_fwd<<<dim3(8, 128), 256, 0, stream>>>(qb, kb, vtb, vals);
    gemm_nt<1><<<dim3(64, 8), 256, 0, stream>>>(vals, woutb, b_out, 8192, 1024, 1024,
                                                out, nullptr, nullptr, nullptr);
}